// Round 9
// baseline (455.622 us; speedup 1.0000x reference)
//
#include <hip/hip_runtime.h>
#include <hip/hip_bf16.h>
#include <stdint.h>

// ArcFace fused: out[n][c] = 64 * margin(clip( (x_hat . w_c) / ||w_c|| ))
// N=512, D=512, C=100000.
// R6 (fourth submit; three broker timeouts): single fused GEMM over raw f32 W
// (no W pre-pass, no fixup pass).
//  - B: reg-staged f32 -> cvt bf16 -> double-buffered LDS (padded stride 40)
//  - A: global_load_lds bf16 (double-buffered, linear layout)
//  - T3 2-phase pipeline: tile t+1 loads issued during tile t stage; ONE
//    vmcnt(0) per iteration (top of next stage) => each load has a full
//    iteration to land. Raw s_barrier + lgkmcnt(0) only (no vmem drain at
//    barriers), sched_barrier(0) fences per rule #18.
//  - per-class sum(w^2) accumulated in-loop; rsqrt + clip + scale + label
//    margin applied in the epilogue (labels staged in LDS).

#define NROWS 512
#define DDIM 512
#define NCLS 100000

typedef __attribute__((ext_vector_type(8))) short bf16x8;
typedef __attribute__((ext_vector_type(8))) unsigned short u16x8;
typedef __attribute__((ext_vector_type(4))) float f32x4;

__device__ __forceinline__ unsigned short f2bf(float x) {
    union { float f; uint32_t u; } c; c.f = x;
    uint32_t r = (c.u + 0x7FFFu + ((c.u >> 16) & 1u)) >> 16;
    return (unsigned short)r;
}

__device__ __forceinline__ void g2lds16(const void* g, void* l) {
    __builtin_amdgcn_global_load_lds(
        (const __attribute__((address_space(1))) void*)g,
        (__attribute__((address_space(3))) void*)l, 16, 0, 0);
}

// Normalize x rows to unit L2 norm, store bf16. 512 rows, one wave each.
__global__ __launch_bounds__(256)
void rownorm_x(const float* __restrict__ in, unsigned short* __restrict__ out) {
    const int row  = blockIdx.x * 4 + (threadIdx.x >> 6);
    const int lane = threadIdx.x & 63;

    const float4* p = (const float4*)(in + (size_t)row * DDIM);
    float4 v0 = p[lane];
    float4 v1 = p[64 + lane];

    float ss = v0.x*v0.x + v0.y*v0.y + v0.z*v0.z + v0.w*v0.w
             + v1.x*v1.x + v1.y*v1.y + v1.z*v1.z + v1.w*v1.w;
    #pragma unroll
    for (int off = 32; off > 0; off >>= 1) ss += __shfl_xor(ss, off);
    const float r = rsqrtf(ss);

    unsigned short* orow = out + (size_t)row * DDIM;
    ushort4 o0, o1;
    o0.x = f2bf(v0.x * r); o0.y = f2bf(v0.y * r);
    o0.z = f2bf(v0.z * r); o0.w = f2bf(v0.w * r);
    o1.x = f2bf(v1.x * r); o1.y = f2bf(v1.y * r);
    o1.z = f2bf(v1.z * r); o1.w = f2bf(v1.w * r);
    *(ushort4*)(orow + lane * 4) = o0;
    *(ushort4*)(orow + 256 + lane * 4) = o1;
}

// 128x128 tile. 256 threads = 4 waves (2x2), each wave a 64x64 sub-tile.
__global__ __launch_bounds__(256)
void arcface_gemm_fused(const unsigned short* __restrict__ A,
                        const float* __restrict__ W,
                        const int* __restrict__ labels,
                        float* __restrict__ out) {
    __shared__ unsigned short As[2][128 * 32];  // 16 KB, linear (gload_lds dest)
    __shared__ unsigned short Bs[2][128 * 40];  // 20 KB, padded stride 40
    __shared__ float ssp[128];
    __shared__ int   lab_s[128];

    const int bid = blockIdx.x;
    // bijective XCD-grouping: the 4 row-slots of a panel share bid%8 residue
    int panel, slot;
    if (bid < 3104) { panel = (bid >> 5) * 8 + (bid & 7); slot = (bid >> 3) & 3; }
    else            { int l = bid - 3104; panel = 776 + l % 6; slot = l / 6; }
    const int rowBase = slot * 128;
    const int colBase = panel * 128;

    const int t    = threadIdx.x;
    const int lane = t & 63;
    const int wid  = t >> 6;
    const int wr   = wid >> 1;
    const int wc   = wid & 1;
    const int kg   = (lane >> 4) << 3;   // k-group offset (bf16 elems)
    const int fr   = lane & 15;

    if (t < 128) lab_s[t] = labels[rowBase + t];

    // B staging geometry: thread t -> class row t>>1, k-half (t&1)*16
    const int brow = t >> 1;
    const int kc   = (t & 1) << 4;
    const int cls  = colBase + brow;
    const bool bv  = cls < NCLS;
    const float* gB = W + (size_t)(bv ? cls : 0) * DDIM + kc;
    unsigned short* wB[2] = { &Bs[0][brow * 40 + kc], &Bs[1][brow * 40 + kc] };

    // A staging geometry (R1 pattern): thread t -> row t>>2 (+64), col (t&3)*8
    const unsigned short* gA = A + (size_t)(rowBase + (t >> 2)) * DDIM + ((t & 3) << 3);

    float ss = 0.f;
    f32x4 acc[4][4] = {};

    // prologue: tile 0 in flight
    float4 p0, p1, p2, p3;
    g2lds16(gA,             &As[0][t * 8]);
    g2lds16(gA + 64 * DDIM, &As[0][2048 + t * 8]);
    if (bv) {
        p0 = *(const float4*)(gB + 0);  p1 = *(const float4*)(gB + 4);
        p2 = *(const float4*)(gB + 8);  p3 = *(const float4*)(gB + 12);
    } else {
        p0 = float4{0,0,0,0}; p1 = p0; p2 = p0; p3 = p0;
    }

    #pragma unroll
    for (int tt = 0; tt < 16; ++tt) {
        const int cur = tt & 1;

        __builtin_amdgcn_s_barrier();            // #1: prev compute's reads done
        __builtin_amdgcn_sched_barrier(0);
        asm volatile("s_waitcnt vmcnt(0)" ::: "memory");  // tile tt fully landed
        __builtin_amdgcn_sched_barrier(0);

        // stage-write tile tt: ss fmac + cvt + 2x ds_write_b128
        ss += p0.x*p0.x + p0.y*p0.y + p0.z*p0.z + p0.w*p0.w;
        ss += p1.x*p1.x + p1.y*p1.y + p1.z*p1.z + p1.w*p1.w;
        ss += p2.x*p2.x + p2.y*p2.y + p2.z*p2.z + p2.w*p2.w;
        ss += p3.x*p3.x + p3.y*p3.y + p3.z*p3.z + p3.w*p3.w;
        u16x8 o0, o1;
        o0[0]=f2bf(p0.x); o0[1]=f2bf(p0.y); o0[2]=f2bf(p0.z); o0[3]=f2bf(p0.w);
        o0[4]=f2bf(p1.x); o0[5]=f2bf(p1.y); o0[6]=f2bf(p1.z); o0[7]=f2bf(p1.w);
        o1[0]=f2bf(p2.x); o1[1]=f2bf(p2.y); o1[2]=f2bf(p2.z); o1[3]=f2bf(p2.w);
        o1[4]=f2bf(p3.x); o1[5]=f2bf(p3.y); o1[6]=f2bf(p3.z); o1[7]=f2bf(p3.w);
        *(u16x8*)(wB[cur])     = o0;
        *(u16x8*)(wB[cur] + 8) = o1;

        // issue tile tt+1 (stays in flight across the barrier; drained by the
        // vmcnt(0) at the TOP of the next iteration => full-iteration cover)
        if (tt < 15) {
            const int kt = (tt + 1) * 32;
            g2lds16(gA + kt,             &As[cur ^ 1][t * 8]);
            g2lds16(gA + kt + 64 * DDIM, &As[cur ^ 1][2048 + t * 8]);
            if (bv) {
                p0 = *(const float4*)(gB + kt + 0);
                p1 = *(const float4*)(gB + kt + 4);
                p2 = *(const float4*)(gB + kt + 8);
                p3 = *(const float4*)(gB + kt + 12);
            }
        }

        asm volatile("s_waitcnt lgkmcnt(0)" ::: "memory");  // ds_writes done
        __builtin_amdgcn_sched_barrier(0);
        __builtin_amdgcn_s_barrier();            // #2: Bs[cur]/As[cur] visible
        __builtin_amdgcn_sched_barrier(0);

        bf16x8 a[4], b[4];
        #pragma unroll
        for (int m = 0; m < 4; ++m)
            a[m] = *(const bf16x8*)&As[cur][(wr * 64 + m * 16 + fr) * 32 + kg];
        #pragma unroll
        for (int n = 0; n < 4; ++n)
            b[n] = *(const bf16x8*)&Bs[cur][(wc * 64 + n * 16 + fr) * 40 + kg];

        #pragma unroll
        for (int m = 0; m < 4; ++m)
            #pragma unroll
            for (int n = 0; n < 4; ++n)
                acc[m][n] = __builtin_amdgcn_mfma_f32_16x16x32_bf16(
                    a[m], b[n], acc[m][n], 0, 0, 0);
    }

    // per-class sum of squares: thread pair (2k, 2k+1) holds the two halves
    float sst = ss + __shfl_xor(ss, 1);
    if ((t & 1) == 0) ssp[t >> 1] = sst;
    __syncthreads();

    const float lo = -1.0f + 1e-7f, hi = 1.0f - 1e-7f;
    const float COSM = 0.8775825618903728f;    // cos(0.5)
    const float SINM = 0.479425538604203f;     // sin(0.5)
    const float MM   = 0.2397127693021015f;    // sin(0.5)*0.5
    const float THR  = -0.8775825618903728f;   // cos(pi-0.5)

    float rn[4];
    #pragma unroll
    for (int n = 0; n < 4; ++n)
        rn[n] = rsqrtf(ssp[wc * 64 + n * 16 + fr]);

    // C/D layout: col = lane&15, row = (lane>>4)*4 + i
    #pragma unroll
    for (int m = 0; m < 4; ++m) {
        const int rloc = wr * 64 + m * 16 + ((lane >> 4) << 2);
        #pragma unroll
        for (int n = 0; n < 4; ++n) {
            const int c = colBase + wc * 64 + n * 16 + fr;
            if (c < NCLS) {
                #pragma unroll
                for (int i = 0; i < 4; ++i) {
                    const float raw = acc[m][n][i] * rn[n];
                    const float tc  = fminf(fmaxf(raw, lo), hi);
                    float val = tc;
                    if (lab_s[rloc + i] == c) {   // label-column margin
                        val = (raw > THR)
                            ? tc * COSM - sqrtf(fmaxf(1.0f - tc * tc, 0.0f)) * SINM
                            : tc - MM;
                    }
                    out[(size_t)(rowBase + rloc + i) * NCLS + c] = 64.0f * val;
                }
            }
        }
    }
}

extern "C" void kernel_launch(void* const* d_in, const int* in_sizes, int n_in,
                              void* d_out, int out_size, void* d_ws, size_t ws_size,
                              hipStream_t stream) {
    const float* x     = (const float*)d_in[0];
    const int*   label = (const int*)d_in[1];
    const float* w     = (const float*)d_in[2];
    float* out = (float*)d_out;

    unsigned short* Abf = (unsigned short*)d_ws;   // 512*512 bf16

    rownorm_x<<<NROWS / 4, 256, 0, stream>>>(x, Abf);

    arcface_gemm_fused<<<3128, 256, 0, stream>>>(Abf, w, label, out);
}